// Round 2
// baseline (746.210 us; speedup 1.0000x reference)
//
#include <hip/hip_runtime.h>
#include <math.h>

#define SCALE 0.17677669529663687f  /* (256/8)^-0.5 */

// ---------------------------------------------------------------------------
// token row -> spatial row index ((b*56+h)*56+w) for windowed row m in [0,25088)
__device__ __forceinline__ int token_row_addr(int m) {
    int b = m / 3136;
    int rem = m - b * 3136;
    int s = rem / 49;
    int tok = rem - s * 49;
    int h = (s >> 3) * 7 + tok / 7;
    int w = (s & 7) * 7 + (tok % 7);
    return (b * 56 + h) * 56 + w;
}

// ---------------------------------------------------------------------------
// K0a: per-region mean. grid 512 (b*64+s), block 256 (=c)
__global__ void k_region_mean(const float* __restrict__ x, float* __restrict__ xr) {
    int blk = blockIdx.x;
    int b = blk >> 6, s = blk & 63;
    int c = threadIdx.x;
    int hy0 = (s >> 3) * 7, wx0 = (s & 7) * 7;
    const float* xb = x + ((size_t)b * 56 * 56) * 256 + c;
    float sum = 0.f;
#pragma unroll 1
    for (int t = 0; t < 49; ++t) {
        int h = hy0 + t / 7, w = wx0 + (t % 7);
        sum += xb[(size_t)(h * 56 + w) * 256];
    }
    xr[(size_t)blk * 256 + c] = sum * (1.0f / 49.0f);
}

// ---------------------------------------------------------------------------
// K0b: qkv_r = x_region @ w_qkv + b_qkv. grid 512, block 256.
__global__ void k_region_qkv(const float* __restrict__ xr, const float* __restrict__ wqkv,
                             const float* __restrict__ bqkv, float* __restrict__ qkvr) {
    __shared__ float xs[256];
    int blk = blockIdx.x;
    int t = threadIdx.x;
    xs[t] = xr[(size_t)blk * 256 + t];
    __syncthreads();
    float a0 = 0.f, a1 = 0.f, a2 = 0.f;
#pragma unroll 4
    for (int k = 0; k < 256; ++k) {
        float xv = xs[k];
        const float* wrow = wqkv + (size_t)k * 768;
        a0 += xv * wrow[t];
        a1 += xv * wrow[t + 256];
        a2 += xv * wrow[t + 512];
    }
    float* o = qkvr + (size_t)blk * 768;
    o[t]       = a0 + bqkv[t];
    o[t + 256] = a1 + bqkv[t + 256];
    o[t + 512] = a2 + bqkv[t + 512];
}

// ---------------------------------------------------------------------------
// K0c: sigma = softplus(relu(q_r@w_g1+b_g1)@w_g2+b_g2)+0.5. grid 512, block 64.
__global__ void k_gating(const float* __restrict__ qkvr, const float* __restrict__ wg1,
                         const float* __restrict__ bg1, const float* __restrict__ wg2,
                         const float* __restrict__ bg2, float* __restrict__ sig) {
    __shared__ float hs[64];
    int blk = blockIdx.x;
    int j = threadIdx.x;
    const float* qr = qkvr + (size_t)blk * 768;  // q part
    float acc = bg1[j];
#pragma unroll 4
    for (int k = 0; k < 256; ++k) acc += qr[k] * wg1[(size_t)k * 64 + j];
    hs[j] = fmaxf(acc, 0.f);
    __syncthreads();
    if (j < 2) {
        float gp = bg2[j];
#pragma unroll 1
        for (int m = 0; m < 64; ++m) gp += hs[m] * wg2[m * 2 + j];
        float sp = fmaxf(gp, 0.f) + log1pf(expf(-fabsf(gp)));
        sig[blk * 2 + j] = sp + 0.5f;
    }
}

// ---------------------------------------------------------------------------
// K0d: A_r row + top-4 (strict argmax, lower index wins ties) + gaussian weights.
__global__ void k_topk_gauss(const float* __restrict__ qkvr, const float* __restrict__ sig,
                             int* __restrict__ topk, float* __restrict__ gwt) {
    __shared__ float A[64];
    __shared__ float G[64];
    __shared__ int idxs[4];
    __shared__ float gsum_s;
    int blk = blockIdx.x;
    int b = blk >> 6, s = blk & 63;
    int z = threadIdx.x;
    const float* qr = qkvr + (size_t)blk * 768;
    const float* kr = qkvr + (size_t)(b * 64 + z) * 768 + 256;
    float acc = 0.f;
#pragma unroll 4
    for (int k = 0; k < 256; k += 4) {
        float4 q4 = *(const float4*)(qr + k);
        float4 k4 = *(const float4*)(kr + k);
        acc += q4.x * k4.x + q4.y * k4.y + q4.z * k4.z + q4.w * k4.w;
    }
    A[z] = acc * SCALE;
    float s0 = sig[blk * 2 + 0], s1 = sig[blk * 2 + 1];
    float dx = (float)((z & 7) - (s & 7));
    float dy = (float)((z >> 3) - (s >> 3));
    float t0 = dx / s0, t1 = dy / s1;
    float zz = t0 * t0 + t1 * t1;
    G[z] = expf(-0.5f * zz);
    __syncthreads();
    if (z == 0) {
        float gs = 0.f;
        for (int m = 0; m < 64; ++m) gs += G[m];
        gsum_s = gs + 1e-6f;
        for (int it = 0; it < 4; ++it) {
            int best = 0;
            float bv = A[0];
            for (int m = 1; m < 64; ++m) {
                if (A[m] > bv) { bv = A[m]; best = m; }
            }
            idxs[it] = best;
            A[best] = -3.0e38f;
        }
    }
    __syncthreads();
    if (z < 4) {
        int id = idxs[z];
        topk[blk * 4 + z] = id;
        gwt[blk * 4 + z] = G[id] / gsum_s;
    }
}

// ---------------------------------------------------------------------------
// K1: qkv GEMM. M=25088 (windowed gather of x rows), K=256, N=768.
__global__ __launch_bounds__(256) void k_qkv_gemm(
    const float* __restrict__ x, const float* __restrict__ wqkv,
    const float* __restrict__ bqkv, float* __restrict__ Q,
    float* __restrict__ Kb, float* __restrict__ V) {
    __shared__ float As[16][68];
    __shared__ float Bs[16][68];
    int tid = threadIdx.x;
    int n0 = blockIdx.x * 64;
    int m0 = blockIdx.y * 64;
    int ty = tid >> 4, tx = tid & 15;
    int ar = tid >> 2;
    int ak = (tid & 3) * 4;
    const float* arow = x + (size_t)token_row_addr(m0 + ar) * 256 + ak;
    int bk = tid >> 4;
    int bc = (tid & 15) * 4;
    const float* bptr = wqkv + (size_t)bk * 768 + n0 + bc;

    float acc[4][4] = {};
#pragma unroll 1
    for (int k0 = 0; k0 < 256; k0 += 16) {
        float4 a4 = *(const float4*)(arow + k0);
        float4 b4 = *(const float4*)(bptr + (size_t)k0 * 768);
        __syncthreads();
        As[ak + 0][ar] = a4.x;
        As[ak + 1][ar] = a4.y;
        As[ak + 2][ar] = a4.z;
        As[ak + 3][ar] = a4.w;
        *(float4*)&Bs[bk][bc] = b4;
        __syncthreads();
#pragma unroll
        for (int kk = 0; kk < 16; ++kk) {
            float4 av4 = *(const float4*)&As[kk][ty * 4];
            float4 bv4 = *(const float4*)&Bs[kk][tx * 4];
            float av[4] = {av4.x, av4.y, av4.z, av4.w};
            float bv[4] = {bv4.x, bv4.y, bv4.z, bv4.w};
#pragma unroll
            for (int i = 0; i < 4; ++i)
#pragma unroll
                for (int j = 0; j < 4; ++j) acc[i][j] += av[i] * bv[j];
        }
    }
    int buf = n0 >> 8;
    int colbase = (n0 & 255) + tx * 4;
    float* dst = (buf == 0) ? Q : (buf == 1 ? Kb : V);
    float4 bias = *(const float4*)(bqkv + n0 + tx * 4);
#pragma unroll
    for (int i = 0; i < 4; ++i) {
        int m = m0 + ty * 4 + i;
        float4 o;
        o.x = acc[i][0] + bias.x;
        o.y = acc[i][1] + bias.y;
        o.z = acc[i][2] + bias.z;
        o.w = acc[i][3] + bias.w;
        *(float4*)(dst + (size_t)m * 256 + colbase) = o;
    }
}

// ---------------------------------------------------------------------------
// K2a: logits + softmax -> P (written into Q buffer slot, stride 256).
// grid 1024: blockIdx.x = win*2 + h; h selects w-rows [h*25, h*25+24] (h=1: 24
// valid rows, row 49 clamped to 48 and never written).
// Thread j (196 of 256) owns key column j: acc[25] regs; Q addresses are
// wave-uniform -> scalar loads; K row float4 loads are L1-resident.
__global__ __launch_bounds__(256) void k_attn_logits(
    const float* __restrict__ Q, const float* __restrict__ Kb,
    const int* __restrict__ topk, const float* __restrict__ gwt,
    float* __restrict__ P) {
    __shared__ float L[25][200];
    __shared__ float red[25][8];
    __shared__ float rowm[25];
    __shared__ float rinv[25];
    int bx = blockIdx.x;
    int win = bx >> 1, h = bx & 1;
    int w0 = h * 25;
    int b = win >> 6;
    int tid = threadIdx.x;

    if (tid < 196) {
        int r = tid / 49, tok = tid - r * 49;
        int reg = topk[win * 4 + r];
        float gw = gwt[win * 4 + r];
        const float* krow = Kb + ((size_t)(b * 64 + reg) * 49 + tok) * 256;
        const float* q0 = Q + ((size_t)win * 49 + w0) * 256;
        // row offset for w=24 (clamp window-row 49 -> 48 when h==1)
        int off24 = (w0 + 24 < 49) ? 24 * 256 : 23 * 256;
        float acc[25];
#pragma unroll
        for (int w = 0; w < 25; ++w) acc[w] = 0.f;
#pragma unroll 2
        for (int kc = 0; kc < 256; kc += 4) {
            float4 k4 = *(const float4*)(krow + kc);
#pragma unroll
            for (int w = 0; w < 25; ++w) {
                int off = (w < 24) ? w * 256 : off24;  // compile-time select
                float4 q4 = *(const float4*)(q0 + off + kc);  // uniform -> s_load
                acc[w] += q4.x * k4.x + q4.y * k4.y + q4.z * k4.z + q4.w * k4.w;
            }
        }
        float sg = SCALE * gw;
#pragma unroll
        for (int w = 0; w < 25; ++w) L[w][tid] = acc[w] * sg;
    }
    __syncthreads();

    // parallel softmax: 8 threads per row
    int r = tid >> 3, p = tid & 7;
    if (tid < 200) {
        float m = -3.0e38f;
        for (int j = p; j < 196; j += 8) m = fmaxf(m, L[r][j]);
        red[r][p] = m;
    }
    __syncthreads();
    if (tid < 25) {
        float m = red[tid][0];
#pragma unroll
        for (int q = 1; q < 8; ++q) m = fmaxf(m, red[tid][q]);
        rowm[tid] = m;
    }
    __syncthreads();
    if (tid < 200) {
        float m = rowm[r], s = 0.f;
        for (int j = p; j < 196; j += 8) {
            float e = expf(L[r][j] - m);
            L[r][j] = e;
            s += e;
        }
        red[r][p] = s;
    }
    __syncthreads();
    if (tid < 25) {
        float s = red[tid][0];
#pragma unroll
        for (int q = 1; q < 8; ++q) s += red[tid][q];
        rinv[tid] = 1.0f / s;
    }
    __syncthreads();
    if (tid < 196) {
#pragma unroll
        for (int w = 0; w < 25; ++w) {
            if (w0 + w < 49)
                P[((size_t)win * 49 + w0 + w) * 256 + tid] = L[w][tid] * rinv[w];
        }
    }
}

// ---------------------------------------------------------------------------
// K2b: out = P @ (gathered V * gwt) + dwconv(V_own). grid 2048:
// blockIdx.x = win*4 + cq (channel quarter). tid -> c = cq*64 + (tid&63),
// wg = tid>>6 (wave-uniform w-group of 13 rows). P reads wave-uniform ->
// scalar loads; V loads coalesced over lanes. No LDS.
__global__ __launch_bounds__(256) void k_attn_pv(
    const float* __restrict__ P, const float* __restrict__ V,
    const int* __restrict__ topk, const float* __restrict__ gwt,
    const float* __restrict__ dwk, const float* __restrict__ dwb,
    float* __restrict__ att) {
    int bx = blockIdx.x;
    int win = bx >> 2, cq = bx & 3;
    int b = win >> 6;
    int tid = threadIdx.x;
    int c = cq * 64 + (tid & 63);
    int wg = tid >> 6;
    int w0 = wg * 13;

    float acc[13];
#pragma unroll
    for (int w = 0; w < 13; ++w) acc[w] = 0.f;

    const float* Pw = P + (size_t)win * 49 * 256;
    // precompute clamped row offsets (uniform)
    int rowoff[13];
#pragma unroll
    for (int w = 0; w < 13; ++w) {
        int row = w0 + w;
        rowoff[w] = (row < 49 ? row : 48) * 256;
    }

#pragma unroll 1
    for (int rr = 0; rr < 4; ++rr) {
        int reg = topk[win * 4 + rr];
        float gw = gwt[win * 4 + rr];
        const float* vb = V + ((size_t)(b * 64 + reg) * 49) * 256 + c;
        const float* pb = Pw + rr * 49;
#pragma unroll 1
        for (int tok = 0; tok < 48; tok += 4) {
            float v0 = vb[(size_t)(tok + 0) * 256] * gw;
            float v1 = vb[(size_t)(tok + 1) * 256] * gw;
            float v2 = vb[(size_t)(tok + 2) * 256] * gw;
            float v3 = vb[(size_t)(tok + 3) * 256] * gw;
#pragma unroll
            for (int w = 0; w < 13; ++w) {
                const float* pr = pb + rowoff[w] + tok;  // uniform -> s_load
                acc[w] += pr[0] * v0 + pr[1] * v1 + pr[2] * v2 + pr[3] * v3;
            }
        }
        { // tok = 48 tail
            float v0 = vb[(size_t)48 * 256] * gw;
#pragma unroll
            for (int w = 0; w < 13; ++w) acc[w] += pb[rowoff[w] + 48] * v0;
        }
    }

    // fused dwconv 3x3 SAME on own-window V + write
    const float* vme = V + (size_t)win * 49 * 256 + c;
    const float* dk = dwk + c;
    float db = dwb[c];
    float* op = att + (size_t)win * 49 * 256 + c;
#pragma unroll
    for (int w = 0; w < 13; ++w) {
        int row = w0 + w;
        if (row < 49) {
            int ty = row / 7, tx = row - ty * 7;
            float vd = db;
#pragma unroll
            for (int dy = 0; dy < 3; ++dy) {
                int yy = ty + dy - 1;
                if (yy < 0 || yy > 6) continue;
#pragma unroll
                for (int dx = 0; dx < 3; ++dx) {
                    int xx = tx + dx - 1;
                    if (xx < 0 || xx > 6) continue;
                    vd += vme[(size_t)(yy * 7 + xx) * 256] * dk[(size_t)(dy * 3 + dx) * 256];
                }
            }
            op[(size_t)row * 256] = acc[w] + vd;
        }
    }
}

// ---------------------------------------------------------------------------
// K3: projection GEMM. M=25088, K=256, N=256, un-windowed scatter + bias.
__global__ __launch_bounds__(256) void k_proj_gemm(
    const float* __restrict__ att, const float* __restrict__ wp,
    const float* __restrict__ bp, float* __restrict__ out) {
    __shared__ float As[16][68];
    __shared__ float Bs[16][68];
    int tid = threadIdx.x;
    int n0 = blockIdx.x * 64;
    int m0 = blockIdx.y * 64;
    int ty = tid >> 4, tx = tid & 15;
    int ar = tid >> 2;
    int ak = (tid & 3) * 4;
    const float* arow = att + (size_t)(m0 + ar) * 256 + ak;
    int bk = tid >> 4;
    int bc = (tid & 15) * 4;
    const float* bptr = wp + (size_t)bk * 256 + n0 + bc;

    float acc[4][4] = {};
#pragma unroll 1
    for (int k0 = 0; k0 < 256; k0 += 16) {
        float4 a4 = *(const float4*)(arow + k0);
        float4 b4 = *(const float4*)(bptr + (size_t)k0 * 256);
        __syncthreads();
        As[ak + 0][ar] = a4.x;
        As[ak + 1][ar] = a4.y;
        As[ak + 2][ar] = a4.z;
        As[ak + 3][ar] = a4.w;
        *(float4*)&Bs[bk][bc] = b4;
        __syncthreads();
#pragma unroll
        for (int kk = 0; kk < 16; ++kk) {
            float4 av4 = *(const float4*)&As[kk][ty * 4];
            float4 bv4 = *(const float4*)&Bs[kk][tx * 4];
            float av[4] = {av4.x, av4.y, av4.z, av4.w};
            float bv[4] = {bv4.x, bv4.y, bv4.z, bv4.w};
#pragma unroll
            for (int i = 0; i < 4; ++i)
#pragma unroll
                for (int j = 0; j < 4; ++j) acc[i][j] += av[i] * bv[j];
        }
    }
    float4 bias = *(const float4*)(bp + n0 + tx * 4);
#pragma unroll
    for (int i = 0; i < 4; ++i) {
        int m = m0 + ty * 4 + i;
        size_t orow = (size_t)token_row_addr(m);
        float4 o;
        o.x = acc[i][0] + bias.x;
        o.y = acc[i][1] + bias.y;
        o.z = acc[i][2] + bias.z;
        o.w = acc[i][3] + bias.w;
        *(float4*)(out + orow * 256 + n0 + tx * 4) = o;
    }
}

// ---------------------------------------------------------------------------
extern "C" void kernel_launch(void* const* d_in, const int* in_sizes, int n_in,
                              void* d_out, int out_size, void* d_ws, size_t ws_size,
                              hipStream_t stream) {
    const float* x    = (const float*)d_in[0];
    const float* wqkv = (const float*)d_in[1];
    const float* bqkv = (const float*)d_in[2];
    const float* wg1  = (const float*)d_in[3];
    const float* bg1  = (const float*)d_in[4];
    const float* wg2  = (const float*)d_in[5];
    const float* bg2  = (const float*)d_in[6];
    const float* dwk  = (const float*)d_in[7];
    const float* dwb  = (const float*)d_in[8];
    const float* wp   = (const float*)d_in[9];
    const float* bp   = (const float*)d_in[10];
    float* out = (float*)d_out;
    float* ws = (float*)d_ws;

    const size_t NTOT = (size_t)25088 * 256;
    float* Q    = ws;          // later overwritten in-place with P (stride 256)
    float* Kbuf = Q + NTOT;
    float* V    = Kbuf + NTOT;
    float* ATT  = V + NTOT;
    float* XR   = ATT + NTOT;
    float* QKVR = XR + 512 * 256;
    float* SIG  = QKVR + 512 * 768;
    float* GWT  = SIG + 1024;
    int*   TOPK = (int*)(GWT + 2048);

    hipLaunchKernelGGL(k_region_mean, dim3(512), dim3(256), 0, stream, x, XR);
    hipLaunchKernelGGL(k_region_qkv, dim3(512), dim3(256), 0, stream, XR, wqkv, bqkv, QKVR);
    hipLaunchKernelGGL(k_gating, dim3(512), dim3(64), 0, stream, QKVR, wg1, bg1, wg2, bg2, SIG);
    hipLaunchKernelGGL(k_topk_gauss, dim3(512), dim3(64), 0, stream, QKVR, SIG, TOPK, GWT);
    hipLaunchKernelGGL(k_qkv_gemm, dim3(12, 392), dim3(256), 0, stream,
                       x, wqkv, bqkv, Q, Kbuf, V);
    hipLaunchKernelGGL(k_attn_logits, dim3(1024), dim3(256), 0, stream,
                       Q, Kbuf, TOPK, GWT, Q /*P in-place*/);
    hipLaunchKernelGGL(k_attn_pv, dim3(2048), dim3(256), 0, stream,
                       Q /*P*/, V, TOPK, GWT, dwk, dwb, ATT);
    hipLaunchKernelGGL(k_proj_gemm, dim3(4, 392), dim3(256), 0, stream, ATT, wp, bp, out);
}

// Round 3
// 512.997 us; speedup vs baseline: 1.4546x; 1.4546x over previous
//
#include <hip/hip_runtime.h>
#include <math.h>

#define SCALE 0.17677669529663687f  /* (256/8)^-0.5 */

// ---------------------------------------------------------------------------
// token row -> spatial row index ((b*56+h)*56+w) for windowed row m in [0,25088)
__device__ __forceinline__ int token_row_addr(int m) {
    int b = m / 3136;
    int rem = m - b * 3136;
    int s = rem / 49;
    int tok = rem - s * 49;
    int h = (s >> 3) * 7 + tok / 7;
    int w = (s & 7) * 7 + (tok % 7);
    return (b * 56 + h) * 56 + w;
}

// ---------------------------------------------------------------------------
// K0a: per-region mean. grid 512 (b*64+s), block 256 (=c)
__global__ void k_region_mean(const float* __restrict__ x, float* __restrict__ xr) {
    int blk = blockIdx.x;
    int b = blk >> 6, s = blk & 63;
    int c = threadIdx.x;
    int hy0 = (s >> 3) * 7, wx0 = (s & 7) * 7;
    const float* xb = x + ((size_t)b * 56 * 56) * 256 + c;
    float sum = 0.f;
#pragma unroll 1
    for (int t = 0; t < 49; ++t) {
        int h = hy0 + t / 7, w = wx0 + (t % 7);
        sum += xb[(size_t)(h * 56 + w) * 256];
    }
    xr[(size_t)blk * 256 + c] = sum * (1.0f / 49.0f);
}

// ---------------------------------------------------------------------------
// K0b: qkv_r = x_region @ w_qkv + b_qkv. grid 512, block 256.
__global__ void k_region_qkv(const float* __restrict__ xr, const float* __restrict__ wqkv,
                             const float* __restrict__ bqkv, float* __restrict__ qkvr) {
    __shared__ float xs[256];
    int blk = blockIdx.x;
    int t = threadIdx.x;
    xs[t] = xr[(size_t)blk * 256 + t];
    __syncthreads();
    float a0 = 0.f, a1 = 0.f, a2 = 0.f;
#pragma unroll 4
    for (int k = 0; k < 256; ++k) {
        float xv = xs[k];
        const float* wrow = wqkv + (size_t)k * 768;
        a0 += xv * wrow[t];
        a1 += xv * wrow[t + 256];
        a2 += xv * wrow[t + 512];
    }
    float* o = qkvr + (size_t)blk * 768;
    o[t]       = a0 + bqkv[t];
    o[t + 256] = a1 + bqkv[t + 256];
    o[t + 512] = a2 + bqkv[t + 512];
}

// ---------------------------------------------------------------------------
// K0c: sigma = softplus(relu(q_r@w_g1+b_g1)@w_g2+b_g2)+0.5. grid 512, block 64.
__global__ void k_gating(const float* __restrict__ qkvr, const float* __restrict__ wg1,
                         const float* __restrict__ bg1, const float* __restrict__ wg2,
                         const float* __restrict__ bg2, float* __restrict__ sig) {
    __shared__ float hs[64];
    int blk = blockIdx.x;
    int j = threadIdx.x;
    const float* qr = qkvr + (size_t)blk * 768;  // q part
    float acc = bg1[j];
#pragma unroll 4
    for (int k = 0; k < 256; ++k) acc += qr[k] * wg1[(size_t)k * 64 + j];
    hs[j] = fmaxf(acc, 0.f);
    __syncthreads();
    if (j < 2) {
        float gp = bg2[j];
#pragma unroll 1
        for (int m = 0; m < 64; ++m) gp += hs[m] * wg2[m * 2 + j];
        float sp = fmaxf(gp, 0.f) + log1pf(expf(-fabsf(gp)));
        sig[blk * 2 + j] = sp + 0.5f;
    }
}

// ---------------------------------------------------------------------------
// K0d: A_r row + top-4 (strict argmax, lower index wins ties) + gaussian weights.
__global__ void k_topk_gauss(const float* __restrict__ qkvr, const float* __restrict__ sig,
                             int* __restrict__ topk, float* __restrict__ gwt) {
    __shared__ float A[64];
    __shared__ float G[64];
    __shared__ int idxs[4];
    __shared__ float gsum_s;
    int blk = blockIdx.x;
    int b = blk >> 6, s = blk & 63;
    int z = threadIdx.x;
    const float* qr = qkvr + (size_t)blk * 768;
    const float* kr = qkvr + (size_t)(b * 64 + z) * 768 + 256;
    float acc = 0.f;
#pragma unroll 4
    for (int k = 0; k < 256; k += 4) {
        float4 q4 = *(const float4*)(qr + k);
        float4 k4 = *(const float4*)(kr + k);
        acc += q4.x * k4.x + q4.y * k4.y + q4.z * k4.z + q4.w * k4.w;
    }
    A[z] = acc * SCALE;
    float s0 = sig[blk * 2 + 0], s1 = sig[blk * 2 + 1];
    float dx = (float)((z & 7) - (s & 7));
    float dy = (float)((z >> 3) - (s >> 3));
    float t0 = dx / s0, t1 = dy / s1;
    float zz = t0 * t0 + t1 * t1;
    G[z] = expf(-0.5f * zz);
    __syncthreads();
    if (z == 0) {
        float gs = 0.f;
        for (int m = 0; m < 64; ++m) gs += G[m];
        gsum_s = gs + 1e-6f;
        for (int it = 0; it < 4; ++it) {
            int best = 0;
            float bv = A[0];
            for (int m = 1; m < 64; ++m) {
                if (A[m] > bv) { bv = A[m]; best = m; }
            }
            idxs[it] = best;
            A[best] = -3.0e38f;
        }
    }
    __syncthreads();
    if (z < 4) {
        int id = idxs[z];
        topk[blk * 4 + z] = id;
        gwt[blk * 4 + z] = G[id] / gsum_s;
    }
}

// ---------------------------------------------------------------------------
// K1: qkv GEMM. M=25088 (windowed gather of x rows), K=256, N=768.
__global__ __launch_bounds__(256) void k_qkv_gemm(
    const float* __restrict__ x, const float* __restrict__ wqkv,
    const float* __restrict__ bqkv, float* __restrict__ Q,
    float* __restrict__ Kb, float* __restrict__ V) {
    __shared__ float As[16][68];
    __shared__ float Bs[16][68];
    int tid = threadIdx.x;
    int n0 = blockIdx.x * 64;
    int m0 = blockIdx.y * 64;
    int ty = tid >> 4, tx = tid & 15;
    int ar = tid >> 2;
    int ak = (tid & 3) * 4;
    const float* arow = x + (size_t)token_row_addr(m0 + ar) * 256 + ak;
    int bk = tid >> 4;
    int bc = (tid & 15) * 4;
    const float* bptr = wqkv + (size_t)bk * 768 + n0 + bc;

    float acc[4][4] = {};
#pragma unroll 1
    for (int k0 = 0; k0 < 256; k0 += 16) {
        float4 a4 = *(const float4*)(arow + k0);
        float4 b4 = *(const float4*)(bptr + (size_t)k0 * 768);
        __syncthreads();
        As[ak + 0][ar] = a4.x;
        As[ak + 1][ar] = a4.y;
        As[ak + 2][ar] = a4.z;
        As[ak + 3][ar] = a4.w;
        *(float4*)&Bs[bk][bc] = b4;
        __syncthreads();
#pragma unroll
        for (int kk = 0; kk < 16; ++kk) {
            float4 av4 = *(const float4*)&As[kk][ty * 4];
            float4 bv4 = *(const float4*)&Bs[kk][tx * 4];
            float av[4] = {av4.x, av4.y, av4.z, av4.w};
            float bv[4] = {bv4.x, bv4.y, bv4.z, bv4.w};
#pragma unroll
            for (int i = 0; i < 4; ++i)
#pragma unroll
                for (int j = 0; j < 4; ++j) acc[i][j] += av[i] * bv[j];
        }
    }
    int buf = n0 >> 8;
    int colbase = (n0 & 255) + tx * 4;
    float* dst = (buf == 0) ? Q : (buf == 1 ? Kb : V);
    float4 bias = *(const float4*)(bqkv + n0 + tx * 4);
#pragma unroll
    for (int i = 0; i < 4; ++i) {
        int m = m0 + ty * 4 + i;
        float4 o;
        o.x = acc[i][0] + bias.x;
        o.y = acc[i][1] + bias.y;
        o.z = acc[i][2] + bias.z;
        o.w = acc[i][3] + bias.w;
        *(float4*)(dst + (size_t)m * 256 + colbase) = o;
    }
}

// ---------------------------------------------------------------------------
// K2a: per-window logits GEMM (4 region chunks of 64x52xK=256, 4x4 micro) +
// in-LDS softmax + transposed P write (gwt folded). grid 512, block 256.
// Pt layout: [win][208 j][52 w], pad rows (tok>=49) are exact zeros.
__global__ __launch_bounds__(256) void k_attn_logits_sm(
    const float* __restrict__ Q, const float* __restrict__ Kb,
    const int* __restrict__ topk, const float* __restrict__ gwt,
    float* __restrict__ Pt) {
    __shared__ float Ls[49][209];   // logits, row stride 209 (odd -> no transp. conflicts)
    __shared__ float As[16][68];    // [k][w-row]
    __shared__ float Bs[16][68];    // [k][tok-col]
    __shared__ float red[49][4];
    __shared__ float rowm[49];
    __shared__ float rinv[49];
    int win = blockIdx.x;
    int b = win >> 6;
    int tid = threadIdx.x;
    int ty = tid >> 4, tx = tid & 15;       // compute mapping: 16 x 16, tx<13 active
    int ar = tid >> 2, ak = (tid & 3) * 4;  // load mapping
    int aw = ar < 49 ? ar : 48;             // clamp pad rows
    const float* qbase = Q + ((size_t)win * 49 + aw) * 256 + ak;

#pragma unroll 1
    for (int r = 0; r < 4; ++r) {
        int reg = topk[win * 4 + r];
        float sg = SCALE * gwt[win * 4 + r];
        int btok = ar < 49 ? ar : 48;
        const float* kbase = Kb + ((size_t)(b * 64 + reg) * 49 + btok) * 256 + ak;
        float acc[4][4] = {};
#pragma unroll 1
        for (int kc = 0; kc < 256; kc += 16) {
            float4 a4 = *(const float4*)(qbase + kc);
            float4 b4 = {0.f, 0.f, 0.f, 0.f};
            if (tid < 208) b4 = *(const float4*)(kbase + kc);
            __syncthreads();
            As[ak + 0][ar] = a4.x;
            As[ak + 1][ar] = a4.y;
            As[ak + 2][ar] = a4.z;
            As[ak + 3][ar] = a4.w;
            if (tid < 208) {
                Bs[ak + 0][ar] = b4.x;
                Bs[ak + 1][ar] = b4.y;
                Bs[ak + 2][ar] = b4.z;
                Bs[ak + 3][ar] = b4.w;
            }
            __syncthreads();
#pragma unroll
            for (int kk = 0; kk < 16; ++kk) {
                float4 av4 = *(const float4*)&As[kk][ty * 4];
                float4 bv4 = *(const float4*)&Bs[kk][tx * 4];
                float av[4] = {av4.x, av4.y, av4.z, av4.w};
                float bv[4] = {bv4.x, bv4.y, bv4.z, bv4.w};
#pragma unroll
                for (int i = 0; i < 4; ++i)
#pragma unroll
                    for (int j = 0; j < 4; ++j) acc[i][j] += av[i] * bv[j];
            }
        }
        // store logits chunk to Ls (mask pads), cols r*52 + tx*4 + j
        if (tx < 13) {
#pragma unroll
            for (int i = 0; i < 4; ++i) {
                int w = ty * 4 + i;
                if (w < 49) {
#pragma unroll
                    for (int j = 0; j < 4; ++j) {
                        int tok = tx * 4 + j;
                        Ls[w][r * 52 + tok] = (tok < 49) ? acc[i][j] * sg : -3.0e38f;
                    }
                }
            }
        }
    }
    __syncthreads();

    // softmax over 208 cols (pads are -3e38 -> exp 0), 4 threads per row
    int sw = tid >> 2, sp = tid & 3;
    if (tid < 196) {
        float m = -3.0e38f;
        for (int j = sp; j < 208; j += 4) m = fmaxf(m, Ls[sw][j]);
        red[sw][sp] = m;
    }
    __syncthreads();
    if (tid < 49)
        rowm[tid] = fmaxf(fmaxf(red[tid][0], red[tid][1]), fmaxf(red[tid][2], red[tid][3]));
    __syncthreads();
    if (tid < 196) {
        float m = rowm[sw], s = 0.f;
        for (int j = sp; j < 208; j += 4) {
            float e = expf(Ls[sw][j] - m);
            Ls[sw][j] = e;
            s += e;
        }
        red[sw][sp] = s;
    }
    __syncthreads();
    if (tid < 49)
        rinv[tid] = 1.0f / (red[tid][0] + red[tid][1] + red[tid][2] + red[tid][3]);
    __syncthreads();

    // transposed write: Pt[win][j][w] = P[w][j] * gwt[r(j)]; coalesced over w
    int w2 = tid & 63, jg = tid >> 6;
    if (w2 < 52) {
        float rv = (w2 < 49) ? rinv[w2] : 0.f;
#pragma unroll 1
        for (int r = 0; r < 4; ++r) {
            float gw = gwt[win * 4 + r];
            float* pt = Pt + ((size_t)win * 208 + r * 52) * 52 + w2;
#pragma unroll 1
            for (int j = jg; j < 52; j += 4) {
                float v = 0.f;
                if (w2 < 49) v = Ls[w2][r * 52 + j] * rv * gw;
                pt[(size_t)j * 52] = v;
            }
        }
    }
}

// ---------------------------------------------------------------------------
// K2b: PV GEMM + fused dwconv. grid 2048 (win*4 + 64-channel chunk), block 256.
// out[w][c] = sum_j Pt[j][w] * V[j][c]; j-tiles of 16 (13 tiles over 208).
__global__ __launch_bounds__(256) void k_attn_pv(
    const float* __restrict__ Pt, const float* __restrict__ V,
    const int* __restrict__ topk, const float* __restrict__ dwk,
    const float* __restrict__ dwb, float* __restrict__ att) {
    __shared__ float As[16][68];  // [j][w]  (cols >=52 garbage, masked at store)
    __shared__ float Vs[16][68];  // [j][c]
    int bx = blockIdx.x;
    int win = bx >> 2, cq = bx & 3, c0 = cq * 64;
    int b = win >> 6;
    int tid = threadIdx.x;
    int jr = tid >> 4, q4 = (tid & 15) * 4;
    int ty = tid >> 4, tx = tid & 15;  // compute: rows w=ty*4.. (ty<13), cols c0+tx*4
    int r0 = topk[win * 4 + 0], r1 = topk[win * 4 + 1];
    int r2 = topk[win * 4 + 2], r3 = topk[win * 4 + 3];

    float acc[4][4] = {};
#pragma unroll 1
    for (int jt = 0; jt < 208; jt += 16) {
        int j = jt + jr;
        float4 a4 = {0.f, 0.f, 0.f, 0.f};
        if (q4 < 52) a4 = *(const float4*)(Pt + ((size_t)win * 208 + j) * 52 + q4);
        int r = (j >= 156) ? 3 : (j >= 104) ? 2 : (j >= 52) ? 1 : 0;
        int reg = (r == 0) ? r0 : (r == 1) ? r1 : (r == 2) ? r2 : r3;
        int tok = j - r * 52;
        tok = tok < 49 ? tok : 48;  // pad rows: Pt row is 0, V value harmless
        float4 v4 = *(const float4*)(V + ((size_t)(b * 64 + reg) * 49 + tok) * 256 + c0 + q4);
        __syncthreads();
        if (q4 < 52) *(float4*)&As[jr][q4] = a4;
        *(float4*)&Vs[jr][q4] = v4;
        __syncthreads();
#pragma unroll
        for (int kk = 0; kk < 16; ++kk) {
            float4 av4 = *(const float4*)&As[kk][ty * 4];
            float4 bv4 = *(const float4*)&Vs[kk][tx * 4];
            float av[4] = {av4.x, av4.y, av4.z, av4.w};
            float bv[4] = {bv4.x, bv4.y, bv4.z, bv4.w};
#pragma unroll
            for (int i = 0; i < 4; ++i)
#pragma unroll
                for (int j2 = 0; j2 < 4; ++j2) acc[i][j2] += av[i] * bv[j2];
        }
    }

    // epilogue: dwconv 3x3 SAME on own-window V + store
    if (ty < 13) {
        const float* vw = V + (size_t)win * 49 * 256 + c0 + tx * 4;
        const float* dk = dwk + c0 + tx * 4;
        float4 db4 = *(const float4*)(dwb + c0 + tx * 4);
#pragma unroll
        for (int i = 0; i < 4; ++i) {
            int w = ty * 4 + i;
            if (w < 49) {
                int py = w / 7, px = w - py * 7;
                float4 vd = db4;
#pragma unroll
                for (int dy = 0; dy < 3; ++dy) {
                    int yy = py + dy - 1;
                    if (yy < 0 || yy > 6) continue;
#pragma unroll
                    for (int dx = 0; dx < 3; ++dx) {
                        int xx = px + dx - 1;
                        if (xx < 0 || xx > 6) continue;
                        float4 vv = *(const float4*)(vw + (size_t)(yy * 7 + xx) * 256);
                        float4 kk4 = *(const float4*)(dk + (size_t)(dy * 3 + dx) * 256);
                        vd.x += vv.x * kk4.x;
                        vd.y += vv.y * kk4.y;
                        vd.z += vv.z * kk4.z;
                        vd.w += vv.w * kk4.w;
                    }
                }
                float4 o;
                o.x = acc[i][0] + vd.x;
                o.y = acc[i][1] + vd.y;
                o.z = acc[i][2] + vd.z;
                o.w = acc[i][3] + vd.w;
                *(float4*)(att + ((size_t)win * 49 + w) * 256 + c0 + tx * 4) = o;
            }
        }
    }
}

// ---------------------------------------------------------------------------
// K3: projection GEMM. M=25088, K=256, N=256, un-windowed scatter + bias.
__global__ __launch_bounds__(256) void k_proj_gemm(
    const float* __restrict__ att, const float* __restrict__ wp,
    const float* __restrict__ bp, float* __restrict__ out) {
    __shared__ float As[16][68];
    __shared__ float Bs[16][68];
    int tid = threadIdx.x;
    int n0 = blockIdx.x * 64;
    int m0 = blockIdx.y * 64;
    int ty = tid >> 4, tx = tid & 15;
    int ar = tid >> 2;
    int ak = (tid & 3) * 4;
    const float* arow = att + (size_t)(m0 + ar) * 256 + ak;
    int bk = tid >> 4;
    int bc = (tid & 15) * 4;
    const float* bptr = wp + (size_t)bk * 256 + n0 + bc;

    float acc[4][4] = {};
#pragma unroll 1
    for (int k0 = 0; k0 < 256; k0 += 16) {
        float4 a4 = *(const float4*)(arow + k0);
        float4 b4 = *(const float4*)(bptr + (size_t)k0 * 256);
        __syncthreads();
        As[ak + 0][ar] = a4.x;
        As[ak + 1][ar] = a4.y;
        As[ak + 2][ar] = a4.z;
        As[ak + 3][ar] = a4.w;
        *(float4*)&Bs[bk][bc] = b4;
        __syncthreads();
#pragma unroll
        for (int kk = 0; kk < 16; ++kk) {
            float4 av4 = *(const float4*)&As[kk][ty * 4];
            float4 bv4 = *(const float4*)&Bs[kk][tx * 4];
            float av[4] = {av4.x, av4.y, av4.z, av4.w};
            float bv[4] = {bv4.x, bv4.y, bv4.z, bv4.w};
#pragma unroll
            for (int i = 0; i < 4; ++i)
#pragma unroll
                for (int j = 0; j < 4; ++j) acc[i][j] += av[i] * bv[j];
        }
    }
    float4 bias = *(const float4*)(bp + n0 + tx * 4);
#pragma unroll
    for (int i = 0; i < 4; ++i) {
        int m = m0 + ty * 4 + i;
        size_t orow = (size_t)token_row_addr(m);
        float4 o;
        o.x = acc[i][0] + bias.x;
        o.y = acc[i][1] + bias.y;
        o.z = acc[i][2] + bias.z;
        o.w = acc[i][3] + bias.w;
        *(float4*)(out + orow * 256 + n0 + tx * 4) = o;
    }
}

// ---------------------------------------------------------------------------
extern "C" void kernel_launch(void* const* d_in, const int* in_sizes, int n_in,
                              void* d_out, int out_size, void* d_ws, size_t ws_size,
                              hipStream_t stream) {
    const float* x    = (const float*)d_in[0];
    const float* wqkv = (const float*)d_in[1];
    const float* bqkv = (const float*)d_in[2];
    const float* wg1  = (const float*)d_in[3];
    const float* bg1  = (const float*)d_in[4];
    const float* wg2  = (const float*)d_in[5];
    const float* bg2  = (const float*)d_in[6];
    const float* dwk  = (const float*)d_in[7];
    const float* dwb  = (const float*)d_in[8];
    const float* wp   = (const float*)d_in[9];
    const float* bp   = (const float*)d_in[10];
    float* out = (float*)d_out;
    float* ws = (float*)d_ws;

    const size_t NTOT = (size_t)25088 * 256;       // 6,422,528
    const size_t PTSZ = (size_t)512 * 208 * 52;    // 5,537,792
    float* A_QATT = ws;               // Q during qkv+logits; ATT after (Q dead)
    float* Kbuf = A_QATT + NTOT;
    float* Vbuf = Kbuf + NTOT;
    float* Pt   = Vbuf + NTOT;
    float* XR   = Pt + PTSZ;
    float* QKVR = XR + 512 * 256;
    float* SIG  = QKVR + 512 * 768;
    float* GWT  = SIG + 1024;
    int*   TOPK = (int*)(GWT + 2048);

    hipLaunchKernelGGL(k_region_mean, dim3(512), dim3(256), 0, stream, x, XR);
    hipLaunchKernelGGL(k_region_qkv, dim3(512), dim3(256), 0, stream, XR, wqkv, bqkv, QKVR);
    hipLaunchKernelGGL(k_gating, dim3(512), dim3(64), 0, stream, QKVR, wg1, bg1, wg2, bg2, SIG);
    hipLaunchKernelGGL(k_topk_gauss, dim3(512), dim3(64), 0, stream, QKVR, SIG, TOPK, GWT);
    hipLaunchKernelGGL(k_qkv_gemm, dim3(12, 392), dim3(256), 0, stream,
                       x, wqkv, bqkv, A_QATT /*Q*/, Kbuf, Vbuf);
    hipLaunchKernelGGL(k_attn_logits_sm, dim3(512), dim3(256), 0, stream,
                       A_QATT /*Q*/, Kbuf, TOPK, GWT, Pt);
    hipLaunchKernelGGL(k_attn_pv, dim3(2048), dim3(256), 0, stream,
                       Pt, Vbuf, TOPK, dwk, dwb, A_QATT /*ATT*/);
    hipLaunchKernelGGL(k_proj_gemm, dim3(4, 392), dim3(256), 0, stream,
                       A_QATT /*ATT*/, wp, bp, out);
}

// Round 4
// 397.165 us; speedup vs baseline: 1.8788x; 1.2916x over previous
//
#include <hip/hip_runtime.h>
#include <math.h>

#define SCALE 0.17677669529663687f  /* (256/8)^-0.5 */

typedef short short8 __attribute__((ext_vector_type(8)));
typedef float f32x4 __attribute__((ext_vector_type(4)));

// ---------------------------------------------------------------------------
__device__ __forceinline__ int token_row_addr(int m) {
    int b = m / 3136;
    int rem = m - b * 3136;
    int s = rem / 49;
    int tok = rem - s * 49;
    int h = (s >> 3) * 7 + tok / 7;
    int w = (s & 7) * 7 + (tok % 7);
    return (b * 56 + h) * 56 + w;
}

// split fp32 -> bf16 hi (truncate) + bf16 lo (residual, truncate)
__device__ __forceinline__ void split2(float x, unsigned short& h, unsigned short& l) {
    unsigned int u = __float_as_uint(x);
    h = (unsigned short)(u >> 16);
    float hf = __uint_as_float(u & 0xFFFF0000u);
    l = (unsigned short)(__float_as_uint(x - hf) >> 16);
}

// async global->LDS 16B per lane; lds dest = wave-uniform base + lane*16
__device__ __forceinline__ void gload16(const unsigned short* g, unsigned short* l) {
    __builtin_amdgcn_global_load_lds(
        (const __attribute__((address_space(1))) unsigned int*)g,
        (__attribute__((address_space(3))) unsigned int*)l, 16, 0, 0);
}

// ---------------------------------------------------------------------------
// converters
// x (spatial) -> xhi/xlo bf16 in WINDOWED row order [25088][256]
__global__ void k_cvt_x(const float* __restrict__ x, unsigned short* __restrict__ xhi,
                        unsigned short* __restrict__ xlo) {
    int m = blockIdx.x;
    int k = threadIdx.x;
    float v = x[(size_t)token_row_addr(m) * 256 + k];
    unsigned short h, l;
    split2(v, h, l);
    xhi[(size_t)m * 256 + k] = h;
    xlo[(size_t)m * 256 + k] = l;
}

// w [K=256 rows][N cols] -> transposed [N][256] hi/lo
__global__ void k_cvt_w(const float* __restrict__ w, int ncols,
                        unsigned short* __restrict__ whi, unsigned short* __restrict__ wlo) {
    int n = blockIdx.x;
    int k = threadIdx.x;
    float v = w[(size_t)k * ncols + n];
    unsigned short h, l;
    split2(v, h, l);
    whi[(size_t)n * 256 + k] = h;
    wlo[(size_t)n * 256 + k] = l;
}

// ---------------------------------------------------------------------------
// K0a..K0d unchanged (fp32 region path)
__global__ void k_region_mean(const float* __restrict__ x, float* __restrict__ xr) {
    int blk = blockIdx.x;
    int b = blk >> 6, s = blk & 63;
    int c = threadIdx.x;
    int hy0 = (s >> 3) * 7, wx0 = (s & 7) * 7;
    const float* xb = x + ((size_t)b * 56 * 56) * 256 + c;
    float sum = 0.f;
#pragma unroll 1
    for (int t = 0; t < 49; ++t) {
        int h = hy0 + t / 7, w = wx0 + (t % 7);
        sum += xb[(size_t)(h * 56 + w) * 256];
    }
    xr[(size_t)blk * 256 + c] = sum * (1.0f / 49.0f);
}

__global__ void k_region_qkv(const float* __restrict__ xr, const float* __restrict__ wqkv,
                             const float* __restrict__ bqkv, float* __restrict__ qkvr) {
    __shared__ float xs[256];
    int blk = blockIdx.x;
    int t = threadIdx.x;
    xs[t] = xr[(size_t)blk * 256 + t];
    __syncthreads();
    float a0 = 0.f, a1 = 0.f, a2 = 0.f;
#pragma unroll 4
    for (int k = 0; k < 256; ++k) {
        float xv = xs[k];
        const float* wrow = wqkv + (size_t)k * 768;
        a0 += xv * wrow[t];
        a1 += xv * wrow[t + 256];
        a2 += xv * wrow[t + 512];
    }
    float* o = qkvr + (size_t)blk * 768;
    o[t]       = a0 + bqkv[t];
    o[t + 256] = a1 + bqkv[t + 256];
    o[t + 512] = a2 + bqkv[t + 512];
}

__global__ void k_gating(const float* __restrict__ qkvr, const float* __restrict__ wg1,
                         const float* __restrict__ bg1, const float* __restrict__ wg2,
                         const float* __restrict__ bg2, float* __restrict__ sig) {
    __shared__ float hs[64];
    int blk = blockIdx.x;
    int j = threadIdx.x;
    const float* qr = qkvr + (size_t)blk * 768;
    float acc = bg1[j];
#pragma unroll 4
    for (int k = 0; k < 256; ++k) acc += qr[k] * wg1[(size_t)k * 64 + j];
    hs[j] = fmaxf(acc, 0.f);
    __syncthreads();
    if (j < 2) {
        float gp = bg2[j];
#pragma unroll 1
        for (int m = 0; m < 64; ++m) gp += hs[m] * wg2[m * 2 + j];
        float sp = fmaxf(gp, 0.f) + log1pf(expf(-fabsf(gp)));
        sig[blk * 2 + j] = sp + 0.5f;
    }
}

__global__ void k_topk_gauss(const float* __restrict__ qkvr, const float* __restrict__ sig,
                             int* __restrict__ topk, float* __restrict__ gwt) {
    __shared__ float A[64];
    __shared__ float G[64];
    __shared__ int idxs[4];
    __shared__ float gsum_s;
    int blk = blockIdx.x;
    int b = blk >> 6, s = blk & 63;
    int z = threadIdx.x;
    const float* qr = qkvr + (size_t)blk * 768;
    const float* kr = qkvr + (size_t)(b * 64 + z) * 768 + 256;
    float acc = 0.f;
#pragma unroll 4
    for (int k = 0; k < 256; k += 4) {
        float4 q4 = *(const float4*)(qr + k);
        float4 k4 = *(const float4*)(kr + k);
        acc += q4.x * k4.x + q4.y * k4.y + q4.z * k4.z + q4.w * k4.w;
    }
    A[z] = acc * SCALE;
    float s0 = sig[blk * 2 + 0], s1 = sig[blk * 2 + 1];
    float dx = (float)((z & 7) - (s & 7));
    float dy = (float)((z >> 3) - (s >> 3));
    float t0 = dx / s0, t1 = dy / s1;
    float zz = t0 * t0 + t1 * t1;
    G[z] = expf(-0.5f * zz);
    __syncthreads();
    if (z == 0) {
        float gs = 0.f;
        for (int m = 0; m < 64; ++m) gs += G[m];
        gsum_s = gs + 1e-6f;
        for (int it = 0; it < 4; ++it) {
            int best = 0;
            float bv = A[0];
            for (int m = 1; m < 64; ++m) {
                if (A[m] > bv) { bv = A[m]; best = m; }
            }
            idxs[it] = best;
            A[best] = -3.0e38f;
        }
    }
    __syncthreads();
    if (z < 4) {
        int id = idxs[z];
        topk[blk * 4 + z] = id;
        gwt[blk * 4 + z] = G[id] / gsum_s;
    }
}

// ---------------------------------------------------------------------------
// K1: qkv GEMM, split-bf16 MFMA. M=25088, K=256, N=768. 128x128 tile, BK=32,
// 4 waves each 64x64 (4x4 tiles of 16x16x32). grid (6, 196).
__global__ __launch_bounds__(256) void k_mm_qkv(
    const unsigned short* __restrict__ xhi, const unsigned short* __restrict__ xlo,
    const unsigned short* __restrict__ whi, const unsigned short* __restrict__ wlo,
    const float* __restrict__ bqkv,
    float* __restrict__ Q, float* __restrict__ Kb, float* __restrict__ V) {
    __shared__ __align__(16) unsigned short Ah[4096];  // [128][32]
    __shared__ __align__(16) unsigned short Al[4096];
    __shared__ __align__(16) unsigned short Bh[4096];
    __shared__ __align__(16) unsigned short Bl[4096];
    int tid = threadIdx.x;
    int ln = tid & 63, wv = tid >> 6;
    int m0 = blockIdx.y * 128, n0 = blockIdx.x * 128;
    int mrow = (wv >> 1) * 64, ncol = (wv & 1) * 64;

    // staging addresses: each wave stages rows wv*32..wv*32+31 of each tile
    int lrow = ln >> 2, lseg = (ln & 3) * 8;
    const unsigned short* gA0 = xhi + (size_t)(m0 + wv * 32 + lrow) * 256 + lseg;
    const unsigned short* gA1 = gA0 + 16 * 256;
    const unsigned short* gAl0 = xlo + (size_t)(m0 + wv * 32 + lrow) * 256 + lseg;
    const unsigned short* gAl1 = gAl0 + 16 * 256;
    const unsigned short* gB0 = whi + (size_t)(n0 + wv * 32 + lrow) * 256 + lseg;
    const unsigned short* gB1 = gB0 + 16 * 256;
    const unsigned short* gBl0 = wlo + (size_t)(n0 + wv * 32 + lrow) * 256 + lseg;
    const unsigned short* gBl1 = gBl0 + 16 * 256;
    unsigned short* lA0 = &Ah[(wv * 32) * 32];
    unsigned short* lA1 = &Ah[(wv * 32 + 16) * 32];
    unsigned short* lAl0 = &Al[(wv * 32) * 32];
    unsigned short* lAl1 = &Al[(wv * 32 + 16) * 32];
    unsigned short* lB0 = &Bh[(wv * 32) * 32];
    unsigned short* lB1 = &Bh[(wv * 32 + 16) * 32];
    unsigned short* lBl0 = &Bl[(wv * 32) * 32];
    unsigned short* lBl1 = &Bl[(wv * 32 + 16) * 32];

    int fm = ln & 15, fq = (ln >> 4) * 8;
    f32x4 acc[4][4];
#pragma unroll
    for (int i = 0; i < 4; ++i)
#pragma unroll
        for (int j = 0; j < 4; ++j) acc[i][j] = (f32x4){0.f, 0.f, 0.f, 0.f};

#pragma unroll 1
    for (int kc = 0; kc < 8; ++kc) {
        if (kc) __syncthreads();
        gload16(gA0, lA0); gload16(gA1, lA1);
        gload16(gAl0, lAl0); gload16(gAl1, lAl1);
        gload16(gB0, lB0); gload16(gB1, lB1);
        gload16(gBl0, lBl0); gload16(gBl1, lBl1);
        gA0 += 32; gA1 += 32; gAl0 += 32; gAl1 += 32;
        gB0 += 32; gB1 += 32; gBl0 += 32; gBl1 += 32;
        __syncthreads();

        short8 ah[4], bh[4], xx[4];
#pragma unroll
        for (int mi = 0; mi < 4; ++mi)
            ah[mi] = *(const short8*)&Ah[(mrow + mi * 16 + fm) * 32 + fq];
#pragma unroll
        for (int ni = 0; ni < 4; ++ni)
            bh[ni] = *(const short8*)&Bh[(ncol + ni * 16 + fm) * 32 + fq];
#pragma unroll
        for (int mi = 0; mi < 4; ++mi)
#pragma unroll
            for (int ni = 0; ni < 4; ++ni)
                acc[mi][ni] = __builtin_amdgcn_mfma_f32_16x16x32_bf16(ah[mi], bh[ni], acc[mi][ni], 0, 0, 0);
#pragma unroll
        for (int mi = 0; mi < 4; ++mi)
            xx[mi] = *(const short8*)&Al[(mrow + mi * 16 + fm) * 32 + fq];
#pragma unroll
        for (int mi = 0; mi < 4; ++mi)
#pragma unroll
            for (int ni = 0; ni < 4; ++ni)
                acc[mi][ni] = __builtin_amdgcn_mfma_f32_16x16x32_bf16(xx[mi], bh[ni], acc[mi][ni], 0, 0, 0);
#pragma unroll
        for (int ni = 0; ni < 4; ++ni)
            xx[ni] = *(const short8*)&Bl[(ncol + ni * 16 + fm) * 32 + fq];
#pragma unroll
        for (int mi = 0; mi < 4; ++mi)
#pragma unroll
            for (int ni = 0; ni < 4; ++ni)
                acc[mi][ni] = __builtin_amdgcn_mfma_f32_16x16x32_bf16(ah[mi], xx[ni], acc[mi][ni], 0, 0, 0);
    }

    // epilogue: C/D layout col=lane&15, row=(lane>>4)*4+reg
    int obuf = n0 >> 8;
    float* dst = (obuf == 0) ? Q : (obuf == 1 ? Kb : V);
    int cb = (n0 & 255) + ncol;
    int qrow = (ln >> 4) * 4;
#pragma unroll
    for (int ni = 0; ni < 4; ++ni) {
        int col = cb + ni * 16 + fm;
        float bias = bqkv[n0 + ncol + ni * 16 + fm];
#pragma unroll
        for (int mi = 0; mi < 4; ++mi) {
#pragma unroll
            for (int r = 0; r < 4; ++r) {
                int m = m0 + mrow + mi * 16 + qrow + r;
                dst[(size_t)m * 256 + col] = acc[mi][ni][r] + bias;
            }
        }
    }
}

// ---------------------------------------------------------------------------
// K2a: logits GEMM + softmax + transposed P write (unchanged fp32)
__global__ __launch_bounds__(256) void k_attn_logits_sm(
    const float* __restrict__ Q, const float* __restrict__ Kb,
    const int* __restrict__ topk, const float* __restrict__ gwt,
    float* __restrict__ Pt) {
    __shared__ float Ls[49][209];
    __shared__ float As[16][68];
    __shared__ float Bs[16][68];
    __shared__ float red[49][4];
    __shared__ float rowm[49];
    __shared__ float rinv[49];
    int win = blockIdx.x;
    int b = win >> 6;
    int tid = threadIdx.x;
    int ty = tid >> 4, tx = tid & 15;
    int ar = tid >> 2, ak = (tid & 3) * 4;
    int aw = ar < 49 ? ar : 48;
    const float* qbase = Q + ((size_t)win * 49 + aw) * 256 + ak;

#pragma unroll 1
    for (int r = 0; r < 4; ++r) {
        int reg = topk[win * 4 + r];
        float sg = SCALE * gwt[win * 4 + r];
        int btok = ar < 49 ? ar : 48;
        const float* kbase = Kb + ((size_t)(b * 64 + reg) * 49 + btok) * 256 + ak;
        float acc[4][4] = {};
#pragma unroll 1
        for (int kc = 0; kc < 256; kc += 16) {
            float4 a4 = *(const float4*)(qbase + kc);
            float4 b4 = {0.f, 0.f, 0.f, 0.f};
            if (tid < 208) b4 = *(const float4*)(kbase + kc);
            __syncthreads();
            As[ak + 0][ar] = a4.x;
            As[ak + 1][ar] = a4.y;
            As[ak + 2][ar] = a4.z;
            As[ak + 3][ar] = a4.w;
            if (tid < 208) {
                Bs[ak + 0][ar] = b4.x;
                Bs[ak + 1][ar] = b4.y;
                Bs[ak + 2][ar] = b4.z;
                Bs[ak + 3][ar] = b4.w;
            }
            __syncthreads();
#pragma unroll
            for (int kk = 0; kk < 16; ++kk) {
                float4 av4 = *(const float4*)&As[kk][ty * 4];
                float4 bv4 = *(const float4*)&Bs[kk][tx * 4];
                float av[4] = {av4.x, av4.y, av4.z, av4.w};
                float bv[4] = {bv4.x, bv4.y, bv4.z, bv4.w};
#pragma unroll
                for (int i = 0; i < 4; ++i)
#pragma unroll
                    for (int j = 0; j < 4; ++j) acc[i][j] += av[i] * bv[j];
            }
        }
        if (tx < 13) {
#pragma unroll
            for (int i = 0; i < 4; ++i) {
                int w = ty * 4 + i;
                if (w < 49) {
#pragma unroll
                    for (int j = 0; j < 4; ++j) {
                        int tok = tx * 4 + j;
                        Ls[w][r * 52 + tok] = (tok < 49) ? acc[i][j] * sg : -3.0e38f;
                    }
                }
            }
        }
    }
    __syncthreads();

    int sw = tid >> 2, sp = tid & 3;
    if (tid < 196) {
        float m = -3.0e38f;
        for (int j = sp; j < 208; j += 4) m = fmaxf(m, Ls[sw][j]);
        red[sw][sp] = m;
    }
    __syncthreads();
    if (tid < 49)
        rowm[tid] = fmaxf(fmaxf(red[tid][0], red[tid][1]), fmaxf(red[tid][2], red[tid][3]));
    __syncthreads();
    if (tid < 196) {
        float m = rowm[sw], s = 0.f;
        for (int j = sp; j < 208; j += 4) {
            float e = expf(Ls[sw][j] - m);
            Ls[sw][j] = e;
            s += e;
        }
        red[sw][sp] = s;
    }
    __syncthreads();
    if (tid < 49)
        rinv[tid] = 1.0f / (red[tid][0] + red[tid][1] + red[tid][2] + red[tid][3]);
    __syncthreads();

    int w2 = tid & 63, jg = tid >> 6;
    if (w2 < 52) {
        float rv = (w2 < 49) ? rinv[w2] : 0.f;
#pragma unroll 1
        for (int r = 0; r < 4; ++r) {
            float gw = gwt[win * 4 + r];
            float* pt = Pt + ((size_t)win * 208 + r * 52) * 52 + w2;
#pragma unroll 1
            for (int j = jg; j < 52; j += 4) {
                float v = 0.f;
                if (w2 < 49) v = Ls[w2][r * 52 + j] * rv * gw;
                pt[(size_t)j * 52] = v;
            }
        }
    }
}

// ---------------------------------------------------------------------------
// K2b: PV GEMM + fused dwconv; epilogue writes ATT as bf16 hi/lo (feeds proj MFMA)
__global__ __launch_bounds__(256) void k_attn_pv(
    const float* __restrict__ Pt, const float* __restrict__ V,
    const int* __restrict__ topk, const float* __restrict__ dwk,
    const float* __restrict__ dwb, unsigned short* __restrict__ atthi,
    unsigned short* __restrict__ attlo) {
    __shared__ float As[16][68];
    __shared__ float Vs[16][68];
    int bx = blockIdx.x;
    int win = bx >> 2, cq = bx & 3, c0 = cq * 64;
    int b = win >> 6;
    int tid = threadIdx.x;
    int jr = tid >> 4, q4 = (tid & 15) * 4;
    int ty = tid >> 4, tx = tid & 15;
    int r0 = topk[win * 4 + 0], r1 = topk[win * 4 + 1];
    int r2 = topk[win * 4 + 2], r3 = topk[win * 4 + 3];

    float acc[4][4] = {};
#pragma unroll 1
    for (int jt = 0; jt < 208; jt += 16) {
        int j = jt + jr;
        float4 a4 = {0.f, 0.f, 0.f, 0.f};
        if (q4 < 52) a4 = *(const float4*)(Pt + ((size_t)win * 208 + j) * 52 + q4);
        int r = (j >= 156) ? 3 : (j >= 104) ? 2 : (j >= 52) ? 1 : 0;
        int reg = (r == 0) ? r0 : (r == 1) ? r1 : (r == 2) ? r2 : r3;
        int tok = j - r * 52;
        tok = tok < 49 ? tok : 48;
        float4 v4 = *(const float4*)(V + ((size_t)(b * 64 + reg) * 49 + tok) * 256 + c0 + q4);
        __syncthreads();
        if (q4 < 52) *(float4*)&As[jr][q4] = a4;
        *(float4*)&Vs[jr][q4] = v4;
        __syncthreads();
#pragma unroll
        for (int kk = 0; kk < 16; ++kk) {
            float4 av4 = *(const float4*)&As[kk][ty * 4];
            float4 bv4 = *(const float4*)&Vs[kk][tx * 4];
            float av[4] = {av4.x, av4.y, av4.z, av4.w};
            float bv[4] = {bv4.x, bv4.y, bv4.z, bv4.w};
#pragma unroll
            for (int i = 0; i < 4; ++i)
#pragma unroll
                for (int j2 = 0; j2 < 4; ++j2) acc[i][j2] += av[i] * bv[j2];
        }
    }

    if (ty < 13) {
        const float* vw = V + (size_t)win * 49 * 256 + c0 + tx * 4;
        const float* dk = dwk + c0 + tx * 4;
        float4 db4 = *(const float4*)(dwb + c0 + tx * 4);
#pragma unroll
        for (int i = 0; i < 4; ++i) {
            int w = ty * 4 + i;
            if (w < 49) {
                int py = w / 7, px = w - py * 7;
                float4 vd = db4;
#pragma unroll
                for (int dy = 0; dy < 3; ++dy) {
                    int yy = py + dy - 1;
                    if (yy < 0 || yy > 6) continue;
#pragma unroll
                    for (int dx = 0; dx < 3; ++dx) {
                        int xx = px + dx - 1;
                        if (xx < 0 || xx > 6) continue;
                        float4 vv = *(const float4*)(vw + (size_t)(yy * 7 + xx) * 256);
                        float4 kk4 = *(const float4*)(dk + (size_t)(dy * 3 + dx) * 256);
                        vd.x += vv.x * kk4.x;
                        vd.y += vv.y * kk4.y;
                        vd.z += vv.z * kk4.z;
                        vd.w += vv.w * kk4.w;
                    }
                }
                float o[4] = {acc[i][0] + vd.x, acc[i][1] + vd.y,
                              acc[i][2] + vd.z, acc[i][3] + vd.w};
                ushort4 oh, ol;
                split2(o[0], oh.x, ol.x);
                split2(o[1], oh.y, ol.y);
                split2(o[2], oh.z, ol.z);
                split2(o[3], oh.w, ol.w);
                size_t idx = ((size_t)win * 49 + w) * 256 + c0 + tx * 4;
                *(ushort4*)(atthi + idx) = oh;
                *(ushort4*)(attlo + idx) = ol;
            }
        }
    }
}

// ---------------------------------------------------------------------------
// K3: proj GEMM, split-bf16 MFMA. M=25088, K=256, N=256. grid (2, 196).
__global__ __launch_bounds__(256) void k_mm_proj(
    const unsigned short* __restrict__ ahi, const unsigned short* __restrict__ alo,
    const unsigned short* __restrict__ whi, const unsigned short* __restrict__ wlo,
    const float* __restrict__ bp, float* __restrict__ out) {
    __shared__ __align__(16) unsigned short Ah[4096];
    __shared__ __align__(16) unsigned short Al[4096];
    __shared__ __align__(16) unsigned short Bh[4096];
    __shared__ __align__(16) unsigned short Bl[4096];
    int tid = threadIdx.x;
    int ln = tid & 63, wv = tid >> 6;
    int m0 = blockIdx.y * 128, n0 = blockIdx.x * 128;
    int mrow = (wv >> 1) * 64, ncol = (wv & 1) * 64;

    int lrow = ln >> 2, lseg = (ln & 3) * 8;
    const unsigned short* gA0 = ahi + (size_t)(m0 + wv * 32 + lrow) * 256 + lseg;
    const unsigned short* gA1 = gA0 + 16 * 256;
    const unsigned short* gAl0 = alo + (size_t)(m0 + wv * 32 + lrow) * 256 + lseg;
    const unsigned short* gAl1 = gAl0 + 16 * 256;
    const unsigned short* gB0 = whi + (size_t)(n0 + wv * 32 + lrow) * 256 + lseg;
    const unsigned short* gB1 = gB0 + 16 * 256;
    const unsigned short* gBl0 = wlo + (size_t)(n0 + wv * 32 + lrow) * 256 + lseg;
    const unsigned short* gBl1 = gBl0 + 16 * 256;
    unsigned short* lA0 = &Ah[(wv * 32) * 32];
    unsigned short* lA1 = &Ah[(wv * 32 + 16) * 32];
    unsigned short* lAl0 = &Al[(wv * 32) * 32];
    unsigned short* lAl1 = &Al[(wv * 32 + 16) * 32];
    unsigned short* lB0 = &Bh[(wv * 32) * 32];
    unsigned short* lB1 = &Bh[(wv * 32 + 16) * 32];
    unsigned short* lBl0 = &Bl[(wv * 32) * 32];
    unsigned short* lBl1 = &Bl[(wv * 32 + 16) * 32];

    int fm = ln & 15, fq = (ln >> 4) * 8;
    f32x4 acc[4][4];
#pragma unroll
    for (int i = 0; i < 4; ++i)
#pragma unroll
        for (int j = 0; j < 4; ++j) acc[i][j] = (f32x4){0.f, 0.f, 0.f, 0.f};

#pragma unroll 1
    for (int kc = 0; kc < 8; ++kc) {
        if (kc) __syncthreads();
        gload16(gA0, lA0); gload16(gA1, lA1);
        gload16(gAl0, lAl0); gload16(gAl1, lAl1);
        gload16(gB0, lB0); gload16(gB1, lB1);
        gload16(gBl0, lBl0); gload16(gBl1, lBl1);
        gA0 += 32; gA1 += 32; gAl0 += 32; gAl1 += 32;
        gB0 += 32; gB1 += 32; gBl0 += 32; gBl1 += 32;
        __syncthreads();

        short8 ah[4], bh[4], xx[4];
#pragma unroll
        for (int mi = 0; mi < 4; ++mi)
            ah[mi] = *(const short8*)&Ah[(mrow + mi * 16 + fm) * 32 + fq];
#pragma unroll
        for (int ni = 0; ni < 4; ++ni)
            bh[ni] = *(const short8*)&Bh[(ncol + ni * 16 + fm) * 32 + fq];
#pragma unroll
        for (int mi = 0; mi < 4; ++mi)
#pragma unroll
            for (int ni = 0; ni < 4; ++ni)
                acc[mi][ni] = __builtin_amdgcn_mfma_f32_16x16x32_bf16(ah[mi], bh[ni], acc[mi][ni], 0, 0, 0);
#pragma unroll
        for (int mi = 0; mi < 4; ++mi)
            xx[mi] = *(const short8*)&Al[(mrow + mi * 16 + fm) * 32 + fq];
#pragma unroll
        for (int mi = 0; mi < 4; ++mi)
#pragma unroll
            for (int ni = 0; ni < 4; ++ni)
                acc[mi][ni] = __builtin_amdgcn_mfma_f32_16x16x32_bf16(xx[mi], bh[ni], acc[mi][ni], 0, 0, 0);
#pragma unroll
        for (int ni = 0; ni < 4; ++ni)
            xx[ni] = *(const short8*)&Bl[(ncol + ni * 16 + fm) * 32 + fq];
#pragma unroll
        for (int mi = 0; mi < 4; ++mi)
#pragma unroll
            for (int ni = 0; ni < 4; ++ni)
                acc[mi][ni] = __builtin_amdgcn_mfma_f32_16x16x32_bf16(ah[mi], xx[ni], acc[mi][ni], 0, 0, 0);
    }

    int qrow = (ln >> 4) * 4;
#pragma unroll
    for (int mi = 0; mi < 4; ++mi) {
#pragma unroll
        for (int r = 0; r < 4; ++r) {
            int m = m0 + mrow + mi * 16 + qrow + r;
            size_t orow = (size_t)token_row_addr(m);
#pragma unroll
            for (int ni = 0; ni < 4; ++ni) {
                int col = n0 + ncol + ni * 16 + fm;
                out[orow * 256 + col] = acc[mi][ni][r] + bp[col];
            }
        }
    }
}

// ---------------------------------------------------------------------------
extern "C" void kernel_launch(void* const* d_in, const int* in_sizes, int n_in,
                              void* d_out, int out_size, void* d_ws, size_t ws_size,
                              hipStream_t stream) {
    const float* x    = (const float*)d_in[0];
    const float* wqkv = (const float*)d_in[1];
    const float* bqkv = (const float*)d_in[2];
    const float* wg1  = (const float*)d_in[3];
    const float* bg1  = (const float*)d_in[4];
    const float* wg2  = (const float*)d_in[5];
    const float* bg2  = (const float*)d_in[6];
    const float* dwk  = (const float*)d_in[7];
    const float* dwb  = (const float*)d_in[8];
    const float* wp   = (const float*)d_in[9];
    const float* bp   = (const float*)d_in[10];
    float* out = (float*)d_out;
    float* ws = (float*)d_ws;

    const size_t NTOT = (size_t)25088 * 256;     // 6,422,528
    const size_t PTSZ = (size_t)512 * 208 * 52;  // 5,537,792
    float* Qf  = ws;
    float* Kf  = Qf + NTOT;
    float* Vf  = Kf + NTOT;
    float* Pt  = Vf + NTOT;
    // bf16 pools (xhi/xlo reused as atthi/attlo after qkv GEMM)
    unsigned short* XH = (unsigned short*)(Pt + PTSZ);   // NTOT shorts
    unsigned short* XL = XH + NTOT;                      // NTOT shorts
    unsigned short* WQH = XL + NTOT;                     // 768*256
    unsigned short* WQL = WQH + 768 * 256;
    unsigned short* WPH = WQL + 768 * 256;               // 256*256
    unsigned short* WPL = WPH + 256 * 256;
    float* XR   = (float*)(WPL + 256 * 256);
    float* QKVR = XR + 512 * 256;
    float* SIG  = QKVR + 512 * 768;
    float* GWT  = SIG + 1024;
    int*   TOPK = (int*)(GWT + 2048);

    hipLaunchKernelGGL(k_cvt_x, dim3(25088), dim3(256), 0, stream, x, XH, XL);
    hipLaunchKernelGGL(k_cvt_w, dim3(768), dim3(256), 0, stream, wqkv, 768, WQH, WQL);
    hipLaunchKernelGGL(k_cvt_w, dim3(256), dim3(256), 0, stream, wp, 256, WPH, WPL);
    hipLaunchKernelGGL(k_region_mean, dim3(512), dim3(256), 0, stream, x, XR);
    hipLaunchKernelGGL(k_region_qkv, dim3(512), dim3(256), 0, stream, XR, wqkv, bqkv, QKVR);
    hipLaunchKernelGGL(k_gating, dim3(512), dim3(64), 0, stream, QKVR, wg1, bg1, wg2, bg2, SIG);
    hipLaunchKernelGGL(k_topk_gauss, dim3(512), dim3(64), 0, stream, QKVR, SIG, TOPK, GWT);
    hipLaunchKernelGGL(k_mm_qkv, dim3(6, 196), dim3(256), 0, stream,
                       XH, XL, WQH, WQL, bqkv, Qf, Kf, Vf);
    hipLaunchKernelGGL(k_attn_logits_sm, dim3(512), dim3(256), 0, stream,
                       Qf, Kf, TOPK, GWT, Pt);
    hipLaunchKernelGGL(k_attn_pv, dim3(2048), dim3(256), 0, stream,
                       Pt, Vf, TOPK, dwk, dwb, XH /*atthi*/, XL /*attlo*/);
    hipLaunchKernelGGL(k_mm_proj, dim3(2, 196), dim3(256), 0, stream,
                       XH, XL, WPH, WPL, bp, out);
}